// Round 5
// baseline (133.333 us; speedup 1.0000x reference)
//
#include <hip/hip_runtime.h>
#include <math.h>

// Problem shape (fixed by setup_inputs): logits [8,12,256,256] fp32, targets [8,256,256] i32.
constexpr int B_  = 8;
constexpr int C_  = 12;
constexpr int H_  = 256;
constexpr int W_  = 256;
constexpr int HW_ = H_ * W_;
constexpr int NBC_ = B_ * C_;           // 96
constexpr int PAD_ = 256;               // LDS row padding (covers max radius 255)

// Packed vertical-EDT value: bit15 = is_fg (t==c); bits[14:0] = vertical
// distance d to nearest zero of the pixel's own nonzero transform
// (0x7FFF = no zero in column -> reference g = 1e6 - h). The OTHER
// transform's g is always 0 at this pixel, so one u16 encodes both.

// ---------------------------------------------------------------------------
// K1: vertical EDT scans, segmented for occupancy.
// Block = 256 threads = 32 columns x 8 segments (32 rows each); 768 blocks.
// Writes packed u16 + per-block hasfg flag (plain store).
// ---------------------------------------------------------------------------
__global__ void k_vert(const int* __restrict__ t,
                       unsigned short* __restrict__ gpk,
                       int* __restrict__ hasfg_p) {
    constexpr int SEG = 8, SH = 32;
    int tid = threadIdx.x;
    int s  = tid >> 5;          // segment
    int wl = tid & 31;          // column within tile
    int blk = blockIdx.x;       // 96*8
    int bc = blk >> 3;
    int w0 = (blk & 7) * 32;
    int b = bc / C_, c = bc - b * C_;
    int w = w0 + wl;
    const int* base = t + b * HW_ + w;
    int h0 = s * SH;

    // Phase A: load targets (packed 4/reg), segment summaries.
    unsigned tp[SH / 4];
    int lastEq = -1, lastNeq = -1, firstEq = 256, firstNeq = 256;
    #pragma unroll 8
    for (int i = 0; i < SH; ++i) {
        int tv = base[(h0 + i) * W_];
        if ((i & 3) == 0) tp[i >> 2] = 0;
        tp[i >> 2] |= (unsigned)tv << ((i & 3) * 8);
        int h = h0 + i;
        if (tv == c) { lastEq = h;  if (firstEq  == 256) firstEq  = h; }
        else         { lastNeq = h; if (firstNeq == 256) firstNeq = h; }
    }
    __shared__ int sLE[SEG][32], sLN[SEG][32], sFE[SEG][32], sFN[SEG][32];
    sLE[s][wl] = lastEq; sLN[s][wl] = lastNeq;
    sFE[s][wl] = firstEq; sFN[s][wl] = firstNeq;
    __syncthreads();

    // Phase B: carries across segments.
    int carLE = -1, carLN = -1;
    for (int q = 0; q < s; ++q) {
        carLE = max(carLE, sLE[q][wl]);
        carLN = max(carLN, sLN[q][wl]);
    }
    int carFE = 256, carFN = 256;
    for (int q = s + 1; q < SEG; ++q) {
        carFE = min(carFE, sFE[q][wl]);
        carFN = min(carFN, sFN[q][wl]);
    }
    bool pred = (s == SEG - 1) && (max(carLE, lastEq) >= 0);
    bool anyfg = __any(pred);
    if (tid == 192) hasfg_p[blk] = anyfg ? 1 : 0;

    // Phase C forward: per-element last-zero indices (registers).
    int pLE[SH], pLN[SH];
    {
        int le = carLE, ln = carLN;
        #pragma unroll
        for (int i = 0; i < SH; ++i) {
            int tv = (tp[i >> 2] >> ((i & 3) * 8)) & 0xFF;
            int h = h0 + i;
            if (tv == c) le = h; else ln = h;
            pLE[i] = le; pLN[i] = ln;
        }
    }
    // Phase C backward: pack distance for the pixel's own nonzero transform.
    {
        int fe = carFE, fn = carFN;
        unsigned short* gk = gpk + (size_t)bc * HW_ + w;
        #pragma unroll
        for (int i = SH - 1; i >= 0; --i) {
            int tv = (tp[i >> 2] >> ((i & 3) * 8)) & 0xFF;
            int h = h0 + i;
            if (tv == c) fe = h; else fn = h;
            bool fg = (tv == c);
            int lastZ = fg ? pLN[i] : pLE[i];
            int nextZ = fg ? fn : fe;
            int dl  = (lastZ < 0)   ? 0x7FFF : (h - lastZ);
            int dnx = (nextZ > 255) ? 0x7FFF : (nextZ - h);
            int d = min(dl, dnx);
            gk[h * W_] = (unsigned short)(d | (fg ? 0x8000 : 0));
        }
    }
}

// ---------------------------------------------------------------------------
// K2 (fused): per-row horizontal EDT + softmax + raw dice sums.
// One wave per (bc,h) row; 4 rows (same bc) per block; no dt materialized.
// Raw sums {S_pd, S_p, S_pp, S_d, S_dd, mn, mx} per row -> part[row*8+k];
// normalization applied algebraically in k_bcred:
//   inter = sc*(S_pd - mn*S_p);  d2 = sc^2*(S_dd - 2 mn S_d + mn^2 N)
// ---------------------------------------------------------------------------
__global__ void k_edt(const unsigned short* __restrict__ gpk,
                      const float* __restrict__ logits,
                      const int* __restrict__ hasfg_p,
                      float* __restrict__ part) {
    __shared__ float sp[4][W_ + 2 * PAD_];
    __shared__ float sn[4][W_ + 2 * PAD_];
    int wave = threadIdx.x >> 6;
    int lane = threadIdx.x & 63;
    int row = blockIdx.x * 4 + wave;       // bc*256 + h; all 4 rows same bc
    int bc = row >> 8;
    int b = bc / C_, c = bc - b * C_;
    int h = row & (H_ - 1);

    int hfl = 0;
    if (lane < 8) hfl = hasfg_p[bc * 8 + lane];
    bool hf = __any(hfl != 0);             // uniform across block (same bc)

    float dv[4];
    if (hf) {
        // pads to +inf-ish
        float4 inf4 = make_float4(3.0e38f, 3.0e38f, 3.0e38f, 3.0e38f);
        ((float4*)&sp[wave][0])[lane]          = inf4;
        ((float4*)&sp[wave][PAD_ + W_])[lane]  = inf4;
        ((float4*)&sn[wave][0])[lane]          = inf4;
        ((float4*)&sn[wave][PAD_ + W_])[lane]  = inf4;

        // decode packed row -> sp/sn
        float s1 = (float)(1000000 - h);
        float sent2 = s1 * s1;             // == fl((1e6 - h)^2), reference-exact
        const ushort4 v4 = ((const ushort4*)(gpk + (size_t)row * W_))[lane];
        float4 fpv, fnv;
        {
            const unsigned short* vs = (const unsigned short*)&v4;
            float* fp = (float*)&fpv;
            float* fn = (float*)&fnv;
            #pragma unroll
            for (int q = 0; q < 4; ++q) {
                unsigned v = vs[q];
                unsigned d = v & 0x7FFFu;
                float g2 = (d == 0x7FFFu) ? sent2 : (float)(d * d);
                bool fg = (v & 0x8000u) != 0;
                fp[q] = fg ? g2 : 0.0f;
                fn[q] = fg ? 0.0f : g2;
            }
        }
        ((float4*)&sp[wave][PAD_])[lane] = fpv;
        ((float4*)&sn[wave][PAD_])[lane] = fnv;
        __syncthreads();                   // hf uniform per block: legal

        float bp[4], bn[4];
        #pragma unroll
        for (int i = 0; i < 4; ++i) {
            int j = PAD_ + lane + 64 * i;
            bp[i] = sp[wave][j];
            bn[i] = sn[wave][j];
        }
        // neg transform expanding search (exact: remaining candidates >= r^2)
        for (int r = 1; r < W_; ++r) {
            float fr = (float)r;
            float r2 = fr * fr;
            float m = fmaxf(fmaxf(bn[0], bn[1]), fmaxf(bn[2], bn[3]));
            if (!__any(r2 < m)) break;
            #pragma unroll
            for (int i = 0; i < 4; ++i) {
                int j = PAD_ + lane + 64 * i;
                float v = fminf(sn[wave][j - r], sn[wave][j + r]);
                bn[i] = fminf(bn[i], fmaf(fr, fr, v));
            }
        }
        // pos transform expanding search
        for (int r = 1; r < W_; ++r) {
            float fr = (float)r;
            float r2 = fr * fr;
            float m = fmaxf(fmaxf(bp[0], bp[1]), fmaxf(bp[2], bp[3]));
            if (!__any(r2 < m)) break;
            #pragma unroll
            for (int i = 0; i < 4; ++i) {
                int j = PAD_ + lane + 64 * i;
                float v = fminf(sp[wave][j - r], sp[wave][j + r]);
                bp[i] = fminf(bp[i], fmaf(fr, fr, v));
            }
        }
        #pragma unroll
        for (int i = 0; i < 4; ++i) dv[i] = sqrtf(bn[i]) - sqrtf(bp[i]);
    } else {
        #pragma unroll
        for (int i = 0; i < 4; ++i) dv[i] = 0.0f;
    }

    // softmax (own class only) + raw sums over this wave's 256 pixels
    const float* lrow = logits + (size_t)b * C_ * HW_ + h * W_;
    float s_pd = 0.f, s_p = 0.f, s_pp = 0.f, s_d = 0.f, s_dd = 0.f;
    float mn = 3.4e38f, mx = -3.4e38f;
    #pragma unroll
    for (int i = 0; i < 4; ++i) {
        int j = lane + 64 * i;
        float l[C_];
        float mxl = -3.4e38f;
        #pragma unroll
        for (int cc = 0; cc < C_; ++cc) { l[cc] = lrow[cc * HW_ + j]; mxl = fmaxf(mxl, l[cc]); }
        float s = 0.f;
        #pragma unroll
        for (int cc = 0; cc < C_; ++cc) { l[cc] = expf(l[cc] - mxl); s += l[cc]; }
        float pr = l[c] * (1.0f / s);
        float d = dv[i];
        s_pd = fmaf(pr, d, s_pd);
        s_p += pr;
        s_pp = fmaf(pr, pr, s_pp);
        s_d += d;
        s_dd = fmaf(d, d, s_dd);
        mn = fminf(mn, d);
        mx = fmaxf(mx, d);
    }
    #pragma unroll
    for (int off = 32; off; off >>= 1) {
        s_pd += __shfl_down(s_pd, off);
        s_p  += __shfl_down(s_p, off);
        s_pp += __shfl_down(s_pp, off);
        s_d  += __shfl_down(s_d, off);
        s_dd += __shfl_down(s_dd, off);
        mn = fminf(mn, __shfl_down(mn, off));
        mx = fmaxf(mx, __shfl_down(mx, off));
    }
    if (lane == 0) {
        float* p8 = part + (size_t)row * 8;
        p8[0] = s_pd; p8[1] = s_p; p8[2] = s_pp;
        p8[3] = s_d;  p8[4] = s_dd; p8[5] = mn; p8[6] = mx;
    }
}

// ---------------------------------------------------------------------------
// K3: per-(b,c) reduce of 256 row partials -> dice -> atomicAdd loss term.
// out[0] must be pre-zeroed (4-byte memset). 96 atomics total: negligible.
// ---------------------------------------------------------------------------
__global__ void k_bcred(const float* __restrict__ part, float* __restrict__ out) {
    int bc = blockIdx.x;
    int tid = threadIdx.x;                 // 256
    const float* p8 = part + ((size_t)bc * 256 + tid) * 8;
    float s_pd = p8[0], s_p = p8[1], s_pp = p8[2];
    float s_d = p8[3], s_dd = p8[4], mn = p8[5], mx = p8[6];
    #pragma unroll
    for (int off = 32; off; off >>= 1) {
        s_pd += __shfl_down(s_pd, off);
        s_p  += __shfl_down(s_p, off);
        s_pp += __shfl_down(s_pp, off);
        s_d  += __shfl_down(s_d, off);
        s_dd += __shfl_down(s_dd, off);
        mn = fminf(mn, __shfl_down(mn, off));
        mx = fmaxf(mx, __shfl_down(mx, off));
    }
    __shared__ float red[4][7];
    int wave = tid >> 6, lane = tid & 63;
    if (lane == 0) {
        red[wave][0] = s_pd; red[wave][1] = s_p; red[wave][2] = s_pp;
        red[wave][3] = s_d;  red[wave][4] = s_dd; red[wave][5] = mn; red[wave][6] = mx;
    }
    __syncthreads();
    if (tid == 0) {
        s_pd = red[0][0]; s_p = red[0][1]; s_pp = red[0][2];
        s_d = red[0][3]; s_dd = red[0][4]; mn = red[0][5]; mx = red[0][6];
        for (int w = 1; w < 4; ++w) {
            s_pd += red[w][0]; s_p += red[w][1]; s_pp += red[w][2];
            s_d += red[w][3]; s_dd += red[w][4];
            mn = fminf(mn, red[w][5]); mx = fmaxf(mx, red[w][6]);
        }
        float sc = 1.0f / (mx - mn + 1e-8f);
        float inter = sc * (s_pd - mn * s_p);
        float d2 = sc * sc * (s_dd - 2.0f * mn * s_d + mn * mn * (float)HW_);
        float dice = 2.0f * inter / (s_pp + d2 + 1e-6f);
        atomicAdd(out, (1.0f - dice) * (1.0f / (float)NBC_));
    }
}

// ---------------------------------------------------------------------------
extern "C" void kernel_launch(void* const* d_in, const int* in_sizes, int n_in,
                              void* d_out, int out_size, void* d_ws, size_t ws_size,
                              hipStream_t stream) {
    const float* logits  = (const float*)d_in[0];
    const int*   targets = (const int*)d_in[1];
    float* out = (float*)d_out;

    // ws layout: gpk u16[96*65536] | hasfg_p i32[768] | part f32[24576*8]
    unsigned short* gpk = (unsigned short*)d_ws;
    int* hasfg_p = (int*)(gpk + (size_t)NBC_ * HW_);
    float* part = (float*)(hasfg_p + NBC_ * 8);

    hipMemsetAsync(out, 0, sizeof(float), stream);
    k_vert<<<NBC_ * 8, 256, 0, stream>>>(targets, gpk, hasfg_p);
    k_edt<<<NBC_ * H_ / 4, 256, 0, stream>>>(gpk, logits, hasfg_p, part);
    k_bcred<<<NBC_, 256, 0, stream>>>(part, out);
}

// Round 6
// 114.336 us; speedup vs baseline: 1.1662x; 1.1662x over previous
//
#include <hip/hip_runtime.h>
#include <math.h>

// Problem shape (fixed by setup_inputs): logits [8,12,256,256] fp32, targets [8,256,256] i32.
constexpr int B_  = 8;
constexpr int C_  = 12;
constexpr int H_  = 256;
constexpr int W_  = 256;
constexpr int HW_ = H_ * W_;
constexpr int NBC_ = B_ * C_;           // 96
constexpr int PAD_ = 256;               // LDS row padding (covers max radius 255)

// Packed vertical-EDT value: bit15 = is_fg (t==c); bits[14:0] = vertical
// distance d to nearest zero of the pixel's own nonzero transform
// (0x7FFF = no zero in column -> reference g = 1e6 - h). The OTHER
// transform's g is always 0 at this pixel, so one u16 encodes both.

// ---------------------------------------------------------------------------
// K1: vertical EDT scans, segmented for occupancy.
// Block = 256 threads = 32 columns x 8 segments (32 rows each); 768 blocks.
// ---------------------------------------------------------------------------
__global__ void k_vert(const int* __restrict__ t,
                       unsigned short* __restrict__ gpk,
                       int* __restrict__ hasfg_p) {
    constexpr int SEG = 8, SH = 32;
    int tid = threadIdx.x;
    int s  = tid >> 5;          // segment
    int wl = tid & 31;          // column within tile
    int blk = blockIdx.x;       // 96*8
    int bc = blk >> 3;
    int w0 = (blk & 7) * 32;
    int b = bc / C_, c = bc - b * C_;
    int w = w0 + wl;
    const int* base = t + b * HW_ + w;
    int h0 = s * SH;

    unsigned tp[SH / 4];
    int lastEq = -1, lastNeq = -1, firstEq = 256, firstNeq = 256;
    #pragma unroll 8
    for (int i = 0; i < SH; ++i) {
        int tv = base[(h0 + i) * W_];
        if ((i & 3) == 0) tp[i >> 2] = 0;
        tp[i >> 2] |= (unsigned)tv << ((i & 3) * 8);
        int h = h0 + i;
        if (tv == c) { lastEq = h;  if (firstEq  == 256) firstEq  = h; }
        else         { lastNeq = h; if (firstNeq == 256) firstNeq = h; }
    }
    __shared__ int sLE[SEG][32], sLN[SEG][32], sFE[SEG][32], sFN[SEG][32];
    sLE[s][wl] = lastEq; sLN[s][wl] = lastNeq;
    sFE[s][wl] = firstEq; sFN[s][wl] = firstNeq;
    __syncthreads();

    int carLE = -1, carLN = -1;
    for (int q = 0; q < s; ++q) {
        carLE = max(carLE, sLE[q][wl]);
        carLN = max(carLN, sLN[q][wl]);
    }
    int carFE = 256, carFN = 256;
    for (int q = s + 1; q < SEG; ++q) {
        carFE = min(carFE, sFE[q][wl]);
        carFN = min(carFN, sFN[q][wl]);
    }
    bool pred = (s == SEG - 1) && (max(carLE, lastEq) >= 0);
    bool anyfg = __any(pred);
    if (tid == 192) hasfg_p[blk] = anyfg ? 1 : 0;

    int pLE[SH], pLN[SH];
    {
        int le = carLE, ln = carLN;
        #pragma unroll
        for (int i = 0; i < SH; ++i) {
            int tv = (tp[i >> 2] >> ((i & 3) * 8)) & 0xFF;
            int h = h0 + i;
            if (tv == c) le = h; else ln = h;
            pLE[i] = le; pLN[i] = ln;
        }
    }
    {
        int fe = carFE, fn = carFN;
        unsigned short* gk = gpk + (size_t)bc * HW_ + w;
        #pragma unroll
        for (int i = SH - 1; i >= 0; --i) {
            int tv = (tp[i >> 2] >> ((i & 3) * 8)) & 0xFF;
            int h = h0 + i;
            if (tv == c) fe = h; else fn = h;
            bool fg = (tv == c);
            int lastZ = fg ? pLN[i] : pLE[i];
            int nextZ = fg ? fn : fe;
            int dl  = (lastZ < 0)   ? 0x7FFF : (h - lastZ);
            int dnx = (nextZ > 255) ? 0x7FFF : (nextZ - h);
            int d = min(dl, dnx);
            gk[h * W_] = (unsigned short)(d | (fg ? 0x8000 : 0));
        }
    }
}

// ---------------------------------------------------------------------------
// K1b: per-pixel softmax stats (computed ONCE, not once per class):
// den[b*HW+p] = {max_c logit, 1/sum_c exp(l-max)}. Same op order as before
// (class-ascending sum of expf) -> bit-identical probabilities downstream.
// ---------------------------------------------------------------------------
__global__ void k_prep(const float* __restrict__ logits, float2* __restrict__ den) {
    int p = blockIdx.x * blockDim.x + threadIdx.x;   // pixel within image
    int b = blockIdx.y;
    const float* lb = logits + (size_t)b * C_ * HW_ + p;
    float l[C_];
    float mxl = -3.4e38f;
    #pragma unroll
    for (int c = 0; c < C_; ++c) { l[c] = lb[c * HW_]; mxl = fmaxf(mxl, l[c]); }
    float s = 0.f;
    #pragma unroll
    for (int c = 0; c < C_; ++c) s += expf(l[c] - mxl);
    den[(size_t)b * HW_ + p] = make_float2(mxl, 1.0f / s);
}

// ---------------------------------------------------------------------------
// K2 (fused): per-row horizontal EDT + own-class prob + raw dice sums.
// One wave per (bc,h) row; 4 rows (same bc) per block; no dt materialized.
// pr = expf(l[c]-mx)*inv  (one expf per pixel-class, stats precomputed).
// Raw sums {S_pd, S_p, S_pp, S_d, S_dd, mn, mx} -> part[row*8+k].
// ---------------------------------------------------------------------------
__global__ void k_edt(const unsigned short* __restrict__ gpk,
                      const float* __restrict__ logits,
                      const float2* __restrict__ den,
                      const int* __restrict__ hasfg_p,
                      float* __restrict__ part) {
    __shared__ float sp[4][W_ + 2 * PAD_];
    __shared__ float sn[4][W_ + 2 * PAD_];
    int wave = threadIdx.x >> 6;
    int lane = threadIdx.x & 63;
    int row = blockIdx.x * 4 + wave;       // bc*256 + h; all 4 rows same bc
    int bc = row >> 8;
    int b = bc / C_, c = bc - b * C_;
    int h = row & (H_ - 1);

    int hfl = 0;
    if (lane < 8) hfl = hasfg_p[bc * 8 + lane];
    bool hf = __any(hfl != 0);             // uniform across block (same bc)

    float dv[4];
    if (hf) {
        float4 inf4 = make_float4(3.0e38f, 3.0e38f, 3.0e38f, 3.0e38f);
        ((float4*)&sp[wave][0])[lane]          = inf4;
        ((float4*)&sp[wave][PAD_ + W_])[lane]  = inf4;
        ((float4*)&sn[wave][0])[lane]          = inf4;
        ((float4*)&sn[wave][PAD_ + W_])[lane]  = inf4;

        float s1 = (float)(1000000 - h);
        float sent2 = s1 * s1;             // == fl((1e6 - h)^2), reference-exact
        const ushort4 v4 = ((const ushort4*)(gpk + (size_t)row * W_))[lane];
        float4 fpv, fnv;
        {
            const unsigned short* vs = (const unsigned short*)&v4;
            float* fp = (float*)&fpv;
            float* fn = (float*)&fnv;
            #pragma unroll
            for (int q = 0; q < 4; ++q) {
                unsigned v = vs[q];
                unsigned d = v & 0x7FFFu;
                float g2 = (d == 0x7FFFu) ? sent2 : (float)(d * d);
                bool fg = (v & 0x8000u) != 0;
                fp[q] = fg ? g2 : 0.0f;
                fn[q] = fg ? 0.0f : g2;
            }
        }
        ((float4*)&sp[wave][PAD_])[lane] = fpv;
        ((float4*)&sn[wave][PAD_])[lane] = fnv;
        __syncthreads();                   // hf uniform per block: legal

        float bp[4], bn[4];
        #pragma unroll
        for (int i = 0; i < 4; ++i) {
            int j = PAD_ + lane + 64 * i;
            bp[i] = sp[wave][j];
            bn[i] = sn[wave][j];
        }
        for (int r = 1; r < W_; ++r) {
            float fr = (float)r;
            float r2 = fr * fr;
            float m = fmaxf(fmaxf(bn[0], bn[1]), fmaxf(bn[2], bn[3]));
            if (!__any(r2 < m)) break;
            #pragma unroll
            for (int i = 0; i < 4; ++i) {
                int j = PAD_ + lane + 64 * i;
                float v = fminf(sn[wave][j - r], sn[wave][j + r]);
                bn[i] = fminf(bn[i], fmaf(fr, fr, v));
            }
        }
        for (int r = 1; r < W_; ++r) {
            float fr = (float)r;
            float r2 = fr * fr;
            float m = fmaxf(fmaxf(bp[0], bp[1]), fmaxf(bp[2], bp[3]));
            if (!__any(r2 < m)) break;
            #pragma unroll
            for (int i = 0; i < 4; ++i) {
                int j = PAD_ + lane + 64 * i;
                float v = fminf(sp[wave][j - r], sp[wave][j + r]);
                bp[i] = fminf(bp[i], fmaf(fr, fr, v));
            }
        }
        #pragma unroll
        for (int i = 0; i < 4; ++i) dv[i] = sqrtf(bn[i]) - sqrtf(bp[i]);
    } else {
        #pragma unroll
        for (int i = 0; i < 4; ++i) dv[i] = 0.0f;
    }

    // own-class prob from precomputed stats + raw sums over 256 pixels
    const float*  lrow = logits + ((size_t)b * C_ + c) * HW_ + h * W_;
    const float2* drow = den + (size_t)b * HW_ + h * W_;
    float s_pd = 0.f, s_p = 0.f, s_pp = 0.f, s_d = 0.f, s_dd = 0.f;
    float mn = 3.4e38f, mx = -3.4e38f;
    #pragma unroll
    for (int i = 0; i < 4; ++i) {
        int j = lane + 64 * i;
        float2 mi = drow[j];
        float pr = expf(lrow[j] - mi.x) * mi.y;
        float d = dv[i];
        s_pd = fmaf(pr, d, s_pd);
        s_p += pr;
        s_pp = fmaf(pr, pr, s_pp);
        s_d += d;
        s_dd = fmaf(d, d, s_dd);
        mn = fminf(mn, d);
        mx = fmaxf(mx, d);
    }
    #pragma unroll
    for (int off = 32; off; off >>= 1) {
        s_pd += __shfl_down(s_pd, off);
        s_p  += __shfl_down(s_p, off);
        s_pp += __shfl_down(s_pp, off);
        s_d  += __shfl_down(s_d, off);
        s_dd += __shfl_down(s_dd, off);
        mn = fminf(mn, __shfl_down(mn, off));
        mx = fmaxf(mx, __shfl_down(mx, off));
    }
    if (lane == 0) {
        float* p8 = part + (size_t)row * 8;
        p8[0] = s_pd; p8[1] = s_p; p8[2] = s_pp;
        p8[3] = s_d;  p8[4] = s_dd; p8[5] = mn; p8[6] = mx;
    }
}

// ---------------------------------------------------------------------------
// K3: per-(b,c) reduce of 256 row partials -> dice -> atomicAdd loss term.
// out[0] pre-zeroed. inter = sc*(S_pd - mn*S_p);
// d2 = sc^2*(S_dd - 2 mn S_d + mn^2 N). 96 atomics total.
// ---------------------------------------------------------------------------
__global__ void k_bcred(const float* __restrict__ part, float* __restrict__ out) {
    int bc = blockIdx.x;
    int tid = threadIdx.x;                 // 256
    const float* p8 = part + ((size_t)bc * 256 + tid) * 8;
    float s_pd = p8[0], s_p = p8[1], s_pp = p8[2];
    float s_d = p8[3], s_dd = p8[4], mn = p8[5], mx = p8[6];
    #pragma unroll
    for (int off = 32; off; off >>= 1) {
        s_pd += __shfl_down(s_pd, off);
        s_p  += __shfl_down(s_p, off);
        s_pp += __shfl_down(s_pp, off);
        s_d  += __shfl_down(s_d, off);
        s_dd += __shfl_down(s_dd, off);
        mn = fminf(mn, __shfl_down(mn, off));
        mx = fmaxf(mx, __shfl_down(mx, off));
    }
    __shared__ float red[4][7];
    int wave = tid >> 6, lane = tid & 63;
    if (lane == 0) {
        red[wave][0] = s_pd; red[wave][1] = s_p; red[wave][2] = s_pp;
        red[wave][3] = s_d;  red[wave][4] = s_dd; red[wave][5] = mn; red[wave][6] = mx;
    }
    __syncthreads();
    if (tid == 0) {
        s_pd = red[0][0]; s_p = red[0][1]; s_pp = red[0][2];
        s_d = red[0][3]; s_dd = red[0][4]; mn = red[0][5]; mx = red[0][6];
        for (int w = 1; w < 4; ++w) {
            s_pd += red[w][0]; s_p += red[w][1]; s_pp += red[w][2];
            s_d += red[w][3]; s_dd += red[w][4];
            mn = fminf(mn, red[w][5]); mx = fmaxf(mx, red[w][6]);
        }
        float sc = 1.0f / (mx - mn + 1e-8f);
        float inter = sc * (s_pd - mn * s_p);
        float d2 = sc * sc * (s_dd - 2.0f * mn * s_d + mn * mn * (float)HW_);
        float dice = 2.0f * inter / (s_pp + d2 + 1e-6f);
        atomicAdd(out, (1.0f - dice) * (1.0f / (float)NBC_));
    }
}

// ---------------------------------------------------------------------------
extern "C" void kernel_launch(void* const* d_in, const int* in_sizes, int n_in,
                              void* d_out, int out_size, void* d_ws, size_t ws_size,
                              hipStream_t stream) {
    const float* logits  = (const float*)d_in[0];
    const int*   targets = (const int*)d_in[1];
    float* out = (float*)d_out;

    // ws layout: gpk u16[96*65536] | hasfg_p i32[768] | part f32[24576*8] |
    //            den float2[8*65536]
    unsigned short* gpk = (unsigned short*)d_ws;
    int* hasfg_p = (int*)(gpk + (size_t)NBC_ * HW_);
    float* part = (float*)(hasfg_p + NBC_ * 8);
    float2* den = (float2*)(part + (size_t)NBC_ * H_ * 8);

    hipMemsetAsync(out, 0, sizeof(float), stream);
    k_vert<<<NBC_ * 8, 256, 0, stream>>>(targets, gpk, hasfg_p);
    k_prep<<<dim3(HW_ / 256, B_), 256, 0, stream>>>(logits, den);
    k_edt<<<NBC_ * H_ / 4, 256, 0, stream>>>(gpk, logits, den, hasfg_p, part);
    k_bcred<<<NBC_, 256, 0, stream>>>(part, out);
}

// Round 7
// 105.588 us; speedup vs baseline: 1.2628x; 1.0828x over previous
//
#include <hip/hip_runtime.h>
#include <math.h>

// Problem shape (fixed by setup_inputs): logits [8,12,256,256] fp32, targets [8,256,256] i32.
constexpr int B_  = 8;
constexpr int C_  = 12;
constexpr int H_  = 256;
constexpr int W_  = 256;
constexpr int HW_ = H_ * W_;
constexpr int NBC_ = B_ * C_;           // 96
constexpr int PAD_ = 256;               // LDS row padding (covers max radius 255)
constexpr int VB_  = NBC_ * 8;          // vert blocks (768)

// Packed vertical-EDT value: bit15 = is_fg (t==c); bits[14:0] = vertical
// distance d to nearest zero of the pixel's own nonzero transform
// (0x7FFF = no zero in column -> reference g = 1e6 - h). The OTHER
// transform's g is always 0 at this pixel, so one u16 encodes both.

// ---------------------------------------------------------------------------
// K1 (merged): blocks [0,768) = vertical EDT scans (32 cols x 8 segments);
// blocks [768, 768+2048) = per-pixel softmax stats den = {max, 1/sum}.
// Independent work co-scheduled in one dispatch; block 0 also zeroes out[0]
// (consumed by k_bcred two dispatches later -- stream order guarantees).
// ---------------------------------------------------------------------------
__global__ void k_vp(const int* __restrict__ t,
                     const float* __restrict__ logits,
                     unsigned short* __restrict__ gpk,
                     int* __restrict__ hasfg_p,
                     float2* __restrict__ den,
                     float* __restrict__ out) {
    int tid = threadIdx.x;
    if (blockIdx.x >= VB_) {
        // ---- softmax-stats branch ----
        int pb = blockIdx.x - VB_;             // [0, 2048)
        int b = pb >> 8;
        int p = ((pb & 255) << 8) + tid;
        const float* lb = logits + (size_t)b * C_ * HW_ + p;
        float l[C_];
        float mxl = -3.4e38f;
        #pragma unroll
        for (int c = 0; c < C_; ++c) { l[c] = lb[c * HW_]; mxl = fmaxf(mxl, l[c]); }
        float s = 0.f;
        #pragma unroll
        for (int c = 0; c < C_; ++c) s += __expf(l[c] - mxl);
        den[(size_t)b * HW_ + p] = make_float2(mxl, 1.0f / s);
        return;
    }

    // ---- vertical EDT branch ----
    if (blockIdx.x == 0 && tid == 0) out[0] = 0.0f;   // replaces memset dispatch
    constexpr int SEG = 8, SH = 32;
    int s  = tid >> 5;          // segment
    int wl = tid & 31;          // column within tile
    int blk = blockIdx.x;       // 96*8
    int bc = blk >> 3;
    int w0 = (blk & 7) * 32;
    int b = bc / C_, c = bc - b * C_;
    int w = w0 + wl;
    const int* base = t + b * HW_ + w;
    int h0 = s * SH;

    unsigned tp[SH / 4];
    int lastEq = -1, lastNeq = -1, firstEq = 256, firstNeq = 256;
    #pragma unroll 8
    for (int i = 0; i < SH; ++i) {
        int tv = base[(h0 + i) * W_];
        if ((i & 3) == 0) tp[i >> 2] = 0;
        tp[i >> 2] |= (unsigned)tv << ((i & 3) * 8);
        int h = h0 + i;
        if (tv == c) { lastEq = h;  if (firstEq  == 256) firstEq  = h; }
        else         { lastNeq = h; if (firstNeq == 256) firstNeq = h; }
    }
    __shared__ int sLE[SEG][32], sLN[SEG][32], sFE[SEG][32], sFN[SEG][32];
    sLE[s][wl] = lastEq; sLN[s][wl] = lastNeq;
    sFE[s][wl] = firstEq; sFN[s][wl] = firstNeq;
    __syncthreads();

    int carLE = -1, carLN = -1;
    for (int q = 0; q < s; ++q) {
        carLE = max(carLE, sLE[q][wl]);
        carLN = max(carLN, sLN[q][wl]);
    }
    int carFE = 256, carFN = 256;
    for (int q = s + 1; q < SEG; ++q) {
        carFE = min(carFE, sFE[q][wl]);
        carFN = min(carFN, sFN[q][wl]);
    }
    bool pred = (s == SEG - 1) && (max(carLE, lastEq) >= 0);
    bool anyfg = __any(pred);
    if (tid == 192) hasfg_p[blk] = anyfg ? 1 : 0;

    int pLE[SH], pLN[SH];
    {
        int le = carLE, ln = carLN;
        #pragma unroll
        for (int i = 0; i < SH; ++i) {
            int tv = (tp[i >> 2] >> ((i & 3) * 8)) & 0xFF;
            int h = h0 + i;
            if (tv == c) le = h; else ln = h;
            pLE[i] = le; pLN[i] = ln;
        }
    }
    {
        int fe = carFE, fn = carFN;
        unsigned short* gk = gpk + (size_t)bc * HW_ + w;
        #pragma unroll
        for (int i = SH - 1; i >= 0; --i) {
            int tv = (tp[i >> 2] >> ((i & 3) * 8)) & 0xFF;
            int h = h0 + i;
            if (tv == c) fe = h; else fn = h;
            bool fg = (tv == c);
            int lastZ = fg ? pLN[i] : pLE[i];
            int nextZ = fg ? fn : fe;
            int dl  = (lastZ < 0)   ? 0x7FFF : (h - lastZ);
            int dnx = (nextZ > 255) ? 0x7FFF : (nextZ - h);
            int d = min(dl, dnx);
            gk[h * W_] = (unsigned short)(d | (fg ? 0x8000 : 0));
        }
    }
}

// ---------------------------------------------------------------------------
// K2 (fused): per-row horizontal EDT + own-class prob + raw dice sums.
// One wave per (bc,h) row; 4 rows (same bc) per block; no dt materialized.
// pr = __expf(l[c]-mx)*inv  (stats precomputed once per pixel).
// Raw sums {S_pd, S_p, S_pp, S_d, S_dd, mn, mx} -> part[row*8+k].
// ---------------------------------------------------------------------------
__global__ void k_edt(const unsigned short* __restrict__ gpk,
                      const float* __restrict__ logits,
                      const float2* __restrict__ den,
                      const int* __restrict__ hasfg_p,
                      float* __restrict__ part) {
    __shared__ float sp[4][W_ + 2 * PAD_];
    __shared__ float sn[4][W_ + 2 * PAD_];
    int wave = threadIdx.x >> 6;
    int lane = threadIdx.x & 63;
    int row = blockIdx.x * 4 + wave;       // bc*256 + h; all 4 rows same bc
    int bc = row >> 8;
    int b = bc / C_, c = bc - b * C_;
    int h = row & (H_ - 1);

    int hfl = 0;
    if (lane < 8) hfl = hasfg_p[bc * 8 + lane];
    bool hf = __any(hfl != 0);             // uniform across block (same bc)

    float dv[4];
    if (hf) {
        float4 inf4 = make_float4(3.0e38f, 3.0e38f, 3.0e38f, 3.0e38f);
        ((float4*)&sp[wave][0])[lane]          = inf4;
        ((float4*)&sp[wave][PAD_ + W_])[lane]  = inf4;
        ((float4*)&sn[wave][0])[lane]          = inf4;
        ((float4*)&sn[wave][PAD_ + W_])[lane]  = inf4;

        float s1 = (float)(1000000 - h);
        float sent2 = s1 * s1;             // == fl((1e6 - h)^2), reference-exact
        const ushort4 v4 = ((const ushort4*)(gpk + (size_t)row * W_))[lane];
        float4 fpv, fnv;
        {
            const unsigned short* vs = (const unsigned short*)&v4;
            float* fp = (float*)&fpv;
            float* fn = (float*)&fnv;
            #pragma unroll
            for (int q = 0; q < 4; ++q) {
                unsigned v = vs[q];
                unsigned d = v & 0x7FFFu;
                float g2 = (d == 0x7FFFu) ? sent2 : (float)(d * d);
                bool fg = (v & 0x8000u) != 0;
                fp[q] = fg ? g2 : 0.0f;
                fn[q] = fg ? 0.0f : g2;
            }
        }
        ((float4*)&sp[wave][PAD_])[lane] = fpv;
        ((float4*)&sn[wave][PAD_])[lane] = fnv;
        __syncthreads();                   // hf uniform per block: legal

        float bp[4], bn[4];
        #pragma unroll
        for (int i = 0; i < 4; ++i) {
            int j = PAD_ + lane + 64 * i;
            bp[i] = sp[wave][j];
            bn[i] = sn[wave][j];
        }
        for (int r = 1; r < W_; ++r) {
            float fr = (float)r;
            float r2 = fr * fr;
            float m = fmaxf(fmaxf(bn[0], bn[1]), fmaxf(bn[2], bn[3]));
            if (!__any(r2 < m)) break;
            #pragma unroll
            for (int i = 0; i < 4; ++i) {
                int j = PAD_ + lane + 64 * i;
                float v = fminf(sn[wave][j - r], sn[wave][j + r]);
                bn[i] = fminf(bn[i], fmaf(fr, fr, v));
            }
        }
        for (int r = 1; r < W_; ++r) {
            float fr = (float)r;
            float r2 = fr * fr;
            float m = fmaxf(fmaxf(bp[0], bp[1]), fmaxf(bp[2], bp[3]));
            if (!__any(r2 < m)) break;
            #pragma unroll
            for (int i = 0; i < 4; ++i) {
                int j = PAD_ + lane + 64 * i;
                float v = fminf(sp[wave][j - r], sp[wave][j + r]);
                bp[i] = fminf(bp[i], fmaf(fr, fr, v));
            }
        }
        #pragma unroll
        for (int i = 0; i < 4; ++i) dv[i] = sqrtf(bn[i]) - sqrtf(bp[i]);
    } else {
        #pragma unroll
        for (int i = 0; i < 4; ++i) dv[i] = 0.0f;
    }

    // own-class prob from precomputed stats + raw sums over 256 pixels
    const float*  lrow = logits + ((size_t)b * C_ + c) * HW_ + h * W_;
    const float2* drow = den + (size_t)b * HW_ + h * W_;
    float s_pd = 0.f, s_p = 0.f, s_pp = 0.f, s_d = 0.f, s_dd = 0.f;
    float mn = 3.4e38f, mx = -3.4e38f;
    #pragma unroll
    for (int i = 0; i < 4; ++i) {
        int j = lane + 64 * i;
        float2 mi = drow[j];
        float pr = __expf(lrow[j] - mi.x) * mi.y;
        float d = dv[i];
        s_pd = fmaf(pr, d, s_pd);
        s_p += pr;
        s_pp = fmaf(pr, pr, s_pp);
        s_d += d;
        s_dd = fmaf(d, d, s_dd);
        mn = fminf(mn, d);
        mx = fmaxf(mx, d);
    }
    #pragma unroll
    for (int off = 32; off; off >>= 1) {
        s_pd += __shfl_down(s_pd, off);
        s_p  += __shfl_down(s_p, off);
        s_pp += __shfl_down(s_pp, off);
        s_d  += __shfl_down(s_d, off);
        s_dd += __shfl_down(s_dd, off);
        mn = fminf(mn, __shfl_down(mn, off));
        mx = fmaxf(mx, __shfl_down(mx, off));
    }
    if (lane == 0) {
        float* p8 = part + (size_t)row * 8;
        p8[0] = s_pd; p8[1] = s_p; p8[2] = s_pp;
        p8[3] = s_d;  p8[4] = s_dd; p8[5] = mn; p8[6] = mx;
    }
}

// ---------------------------------------------------------------------------
// K3: per-(b,c) reduce of 256 row partials -> dice -> atomicAdd loss term.
// out[0] zeroed by k_vp block 0. inter = sc*(S_pd - mn*S_p);
// d2 = sc^2*(S_dd - 2 mn S_d + mn^2 N). 96 atomics total.
// ---------------------------------------------------------------------------
__global__ void k_bcred(const float* __restrict__ part, float* __restrict__ out) {
    int bc = blockIdx.x;
    int tid = threadIdx.x;                 // 256
    const float* p8 = part + ((size_t)bc * 256 + tid) * 8;
    float s_pd = p8[0], s_p = p8[1], s_pp = p8[2];
    float s_d = p8[3], s_dd = p8[4], mn = p8[5], mx = p8[6];
    #pragma unroll
    for (int off = 32; off; off >>= 1) {
        s_pd += __shfl_down(s_pd, off);
        s_p  += __shfl_down(s_p, off);
        s_pp += __shfl_down(s_pp, off);
        s_d  += __shfl_down(s_d, off);
        s_dd += __shfl_down(s_dd, off);
        mn = fminf(mn, __shfl_down(mn, off));
        mx = fmaxf(mx, __shfl_down(mx, off));
    }
    __shared__ float red[4][7];
    int wave = tid >> 6, lane = tid & 63;
    if (lane == 0) {
        red[wave][0] = s_pd; red[wave][1] = s_p; red[wave][2] = s_pp;
        red[wave][3] = s_d;  red[wave][4] = s_dd; red[wave][5] = mn; red[wave][6] = mx;
    }
    __syncthreads();
    if (tid == 0) {
        s_pd = red[0][0]; s_p = red[0][1]; s_pp = red[0][2];
        s_d = red[0][3]; s_dd = red[0][4]; mn = red[0][5]; mx = red[0][6];
        for (int w = 1; w < 4; ++w) {
            s_pd += red[w][0]; s_p += red[w][1]; s_pp += red[w][2];
            s_d += red[w][3]; s_dd += red[w][4];
            mn = fminf(mn, red[w][5]); mx = fmaxf(mx, red[w][6]);
        }
        float sc = 1.0f / (mx - mn + 1e-8f);
        float inter = sc * (s_pd - mn * s_p);
        float d2 = sc * sc * (s_dd - 2.0f * mn * s_d + mn * mn * (float)HW_);
        float dice = 2.0f * inter / (s_pp + d2 + 1e-6f);
        atomicAdd(out, (1.0f - dice) * (1.0f / (float)NBC_));
    }
}

// ---------------------------------------------------------------------------
extern "C" void kernel_launch(void* const* d_in, const int* in_sizes, int n_in,
                              void* d_out, int out_size, void* d_ws, size_t ws_size,
                              hipStream_t stream) {
    const float* logits  = (const float*)d_in[0];
    const int*   targets = (const int*)d_in[1];
    float* out = (float*)d_out;

    // ws layout: gpk u16[96*65536] | hasfg_p i32[768] | part f32[24576*8] |
    //            den float2[8*65536]
    unsigned short* gpk = (unsigned short*)d_ws;
    int* hasfg_p = (int*)(gpk + (size_t)NBC_ * HW_);
    float* part = (float*)(hasfg_p + NBC_ * 8);
    float2* den = (float2*)(part + (size_t)NBC_ * H_ * 8);

    k_vp<<<VB_ + B_ * (HW_ / 256), 256, 0, stream>>>(targets, logits, gpk,
                                                     hasfg_p, den, out);
    k_edt<<<NBC_ * H_ / 4, 256, 0, stream>>>(gpk, logits, den, hasfg_p, part);
    k_bcred<<<NBC_, 256, 0, stream>>>(part, out);
}